// Round 11
// baseline (82.224 us; speedup 1.0000x reference)
//
#include <hip/hip_runtime.h>
#include <math.h>

// Problem constants (reference: N=8, MA=24, DESIGN=26, RADIAL=15, SOFTENING=3, RM=5.0)
constexpr int MAC  = 24;            // atoms per molecule
constexpr int DES  = 26;            // sphere design points
constexpr int RAD  = 15;            // radial points
constexpr int MS   = RAD * DES;     // 390 samples per atom
constexpr int MX   = MAC * MS;      // 9360 grid points per molecule
constexpr int PRM  = MX / 2;        // 4680 point-pairs per molecule
constexpr int GPB  = 8;             // 32-lane groups per block (256 threads)
constexpr int ITER = 4;             // consecutive pairs per group
                                    // group's 4 pairs never span a molecule (4 | 4680)

typedef float v2f __attribute__((ext_vector_type(2)));

__device__ __forceinline__ v2f pk_fma(v2f a, v2f b, v2f c) {
    return __builtin_elementwise_fma(a, b, c);   // -> v_pk_fma_f32
}

// xor-butterfly step within each 32-lane half (bit-mode ds_swizzle)
template <int M>
__device__ __forceinline__ float xorswz(float v) {
    return __int_as_float(__builtin_amdgcn_ds_swizzle(__float_as_int(v), (M << 10) | 0x1f));
}
// DPP cross-lane permute (VALU pipe, not DS)
template <int CTRL>
__device__ __forceinline__ float dppx(float v) {
    return __int_as_float(__builtin_amdgcn_update_dpp(
        0, __float_as_int(v), CTRL, 0xf, 0xf, true));
}

// ---------------------------------------------------------------------------
// Precompute (gridded): tables into d_ws.
//   inv_dm [nmol][24][24], conc4 [390] = {r*sx, r*sy, r*sz, sw*w},
//   cpad   [nmol][24]     = coords padded to float4
// ---------------------------------------------------------------------------
__global__ __launch_bounds__(256) void becke_pre(
    const float* __restrict__ coords, const float* __restrict__ sphere,
    const float* __restrict__ sw, int nmol,
    float* __restrict__ inv_dm, float4* __restrict__ conc4, float4* __restrict__ cpad)
{
    const int e = blockIdx.x * 256 + threadIdx.x;
    const int nidm = nmol * MAC * MAC;
    if (e < nidm) {
        int n = e / (MAC * MAC), r0 = e - n * MAC * MAC;
        int i = r0 / MAC, j = r0 - i * MAC;
        const float* cb = coords + n * MAC * 3;
        float dx = cb[i * 3 + 0] - cb[j * 3 + 0];
        float dy = cb[i * 3 + 1] - cb[j * 3 + 1];
        float dz = cb[i * 3 + 2] - cb[j * 3 + 2];
        float dd = sqrtf(dx * dx + dy * dy + dz * dz);
        inv_dm[e] = 1.0f / fmaxf(dd, 1e-12f);
        return;
    }
    const int e2 = e - nidm;
    if (e2 < MS) {
        int k = e2 / DES, d = e2 - k * DES;
        double i   = (double)k + 1.0;
        double z   = -cos(M_PI * (2.0 * i - 1.0) / (2.0 * (double)RAD));
        double omz = 1.0 - z;
        double dr  = 10.0 / (omz * omz);            // 2*RM, RM = 5.0
        double r   = 5.0 * (1.0 + z) / omz;
        double w1  = sqrt(1.0 - z * z) * dr * M_PI / (double)RAD;
        double w   = r * r * 4.0 * M_PI * w1;
        conc4[e2] = make_float4((float)(r * (double)sphere[d * 3 + 0]),
                                (float)(r * (double)sphere[d * 3 + 1]),
                                (float)(r * (double)sphere[d * 3 + 2]),
                                (float)((double)sw[d] * w));
        return;
    }
    const int e3 = e2 - MS;
    if (e3 < nmol * MAC) {
        cpad[e3] = make_float4(coords[e3 * 3 + 0], coords[e3 * 3 + 1],
                               coords[e3 * 3 + 2], 0.0f);
    }
}

// ---------------------------------------------------------------------------
// Hot kernel, persistent-ish: 1,170 blocks x 8 groups x 4 consecutive pairs.
// Per group: molecule n, lane-atom coords ci, and the inv_dm row are loaded
// ONCE and reused across all 4 pairs. Packed-pair (v_pk_*) mu chains; DPP +
// one ds_swizzle reduction. No __syncthreads.
// ---------------------------------------------------------------------------
__global__ __launch_bounds__(256, 4) void becke_main(
    const float4* __restrict__ cpad,    // [nmol*24]
    const float*  __restrict__ inv_dm,  // [nmol*24*24]
    const float4* __restrict__ conc4,   // [390]
    float* __restrict__ og,             // [nmol, MX, 3]
    float* __restrict__ odv,            // [nmol, MX, 24, 3]
    float* __restrict__ ow)             // [nmol, MX]
{
    __shared__ v2f rxp[GPB][32];        // one rx pair per lane, 2 KB

    const int tid = threadIdx.x;
    const int l   = tid & 31;
    const int grp = tid >> 5;
    const int g   = blockIdx.x * GPB + grp;        // global group id
    const int P0  = g * ITER;                      // first pair of this group
    const int n   = P0 / PRM;                      // molecule (group-constant)
    const int s00 = (P0 - n * PRM) * 2;            // first point in molecule
    const bool act = (l < MAC);
    const int  i   = act ? l : (MAC - 1);

    const float4 ci = cpad[n * MAC + i];           // lane's atom (group-const)

    // lane's inv_dm row: 6 x dwordx4 — loaded ONCE, reused for 8 points
    float inv[MAC];
    {
        const float* irow = inv_dm + (n * MAC + i) * MAC;
        #pragma unroll
        for (int q = 0; q < MAC / 4; ++q) {
            float4 v = *reinterpret_cast<const float4*>(irow + q * 4);
            inv[q * 4 + 0] = v.x; inv[q * 4 + 1] = v.y;
            inv[q * 4 + 2] = v.z; inv[q * 4 + 3] = v.w;
        }
    }

    const v2f cm05 = {-0.5f, -0.5f}, c15 = {1.5f, 1.5f}, c05 = {0.5f, 0.5f};

    for (int it = 0; it < ITER; ++it) {
        const int s0 = s00 + it * 2;               // two points: s0, s0+1
        int ap[2];
        float gx[2], gy[2], gz[2], wt[2], rx[2];
        const size_t sgb = (size_t)n * MX + s0;
        float* dvp = odv + (sgb * MAC + i) * 3;    // p-stride = 72 floats

        #pragma unroll
        for (int p = 0; p < 2; ++p) {
            int sp = s0 + p;
            ap[p] = sp / MS;                       // magic-div (const 390)
            int tp = sp - ap[p] * MS;
            float4 cc = conc4[tp];
            float4 ca = cpad[n * MAC + ap[p]];
            gx[p] = ca.x + cc.x;
            gy[p] = ca.y + cc.y;
            gz[p] = ca.z + cc.z;
            wt[p] = cc.w;
            float dx = gx[p] - ci.x;
            float dy = gy[p] - ci.y;
            float dz = gz[p] - ci.z;
            if (act) {
                dvp[p * MAC * 3 + 0] = dx;         // contiguous -> dwordx3
                dvp[p * MAC * 3 + 1] = dy;
                dvp[p * MAC * 3 + 2] = dz;
            }
            rx[p] = __builtin_amdgcn_sqrtf(dx * dx + dy * dy + dz * dz);
        }
        rxp[grp][l] = (v2f){rx[0], rx[1]};         // wave-synchronous exchange
        __builtin_amdgcn_wave_barrier();           // ordering only; DS in-order

        const v2f rxi = {rx[0], rx[1]};
        v2f prod = {1.0f, 1.0f};

        // Becke row product, diagonal included (s(0)=0.5 exactly, undone by *2)
        #pragma unroll
        for (int jj = 0; jj < MAC / 2; ++jj) {
            // b128 broadcast: {rx0(j0), rx1(j0), rx0(j1), rx1(j1)}
            float4 v4 = *reinterpret_cast<const float4*>(&rxp[grp][2 * jj]);
            const v2f iva = {inv[2 * jj],     inv[2 * jj]};
            const v2f ivb = {inv[2 * jj + 1], inv[2 * jj + 1]};
            v2f mu = (rxi - (v2f){v4.x, v4.y}) * iva;
            mu = mu * pk_fma(mu * mu, cm05, c15);      // soften 1
            mu = mu * pk_fma(mu * mu, cm05, c15);      // soften 2
            prod = prod * pk_fma(mu, cm05, c05);       // *= s
            v2f mv = (rxi - (v2f){v4.z, v4.w}) * ivb;
            mv = mv * pk_fma(mv * mv, cm05, c15);
            mv = mv * pk_fma(mv * mv, cm05, c15);
            prod = prod * pk_fma(mv, cm05, c05);
        }
        __builtin_amdgcn_wave_barrier();           // keep next-iter ds_write after reads

        // mask pad lanes to 0, fold diagonal-undo factor 2
        const v2f cell = prod * (act ? (v2f){2.0f, 2.0f} : (v2f){0.0f, 0.0f});

        #pragma unroll
        for (int p = 0; p < 2; ++p) {
            float c  = (p == 0) ? cell.x : cell.y;
            float su = c;
            su += dppx<0xB1>(su);    // + lane^1
            su += dppx<0x4E>(su);    // + lane^2
            su += dppx<0x141>(su);   // + lane^4 (row_half_mirror)
            su += dppx<0x140>(su);   // + lane^8 (row_mirror)
            su += xorswz<16>(su);    // + lane^16 (single DS op)
            if (l == ap[p])          // lane a holds cell_a; rcp ok (2% slack)
                ow[sgb + p] = c * __builtin_amdgcn_rcpf(su) * wt[p];
        }

        if (l >= MAC && l < MAC + 2) {   // pad lanes 24..25 store grid points
            int p = l - MAC;
            float* gp = og + (sgb + p) * 3;
            gp[0] = gx[p]; gp[1] = gy[p]; gp[2] = gz[p];
        }
    }
}

extern "C" void kernel_launch(void* const* d_in, const int* in_sizes, int n_in,
                              void* d_out, int out_size, void* d_ws, size_t ws_size,
                              hipStream_t stream) {
    // inputs: [0]=labels (unused), [1]=coords f32 [N,24,3],
    //         [2]=sphere f32 [26,3], [3]=sphere_weights f32 [26]
    const float* coords = (const float*)d_in[1];
    const float* sphere = (const float*)d_in[2];
    const float* sw     = (const float*)d_in[3];

    const int nmol = in_sizes[1] / (MAC * 3);   // 8

    float*  ws     = (float*)d_ws;
    float*  inv_dm = ws;                                           // nmol*576 floats
    float4* conc4  = (float4*)(inv_dm + (size_t)nmol * MAC * MAC); // 390 float4
    float4* cpad   = conc4 + MS;                                   // nmol*24 float4

    float* o     = (float*)d_out;
    float* ogrid = o;                                        // [N, MX, 3]
    float* odv   = ogrid + (size_t)nmol * MX * 3;            // [N, MX, 24, 3]
    float* owt   = odv + (size_t)nmol * MX * MAC * 3;        // [N, MX]

    const int pre_elems  = nmol * MAC * MAC + MS + nmol * MAC;
    const int pre_blocks = (pre_elems + 255) / 256;
    becke_pre<<<dim3(pre_blocks), dim3(256), 0, stream>>>(
        coords, sphere, sw, nmol, inv_dm, conc4, cpad);

    // total pairs = nmol*PRM; each block covers GPB groups x ITER pairs = 32
    const int nblocks = (nmol * PRM) / (GPB * ITER);   // 1170 for nmol=8 (exact)
    becke_main<<<dim3(nblocks), dim3(256), 0, stream>>>(
        cpad, inv_dm, conc4, ogrid, odv, owt);
}

// Round 12
// 81.497 us; speedup vs baseline: 1.0089x; 1.0089x over previous
//
#include <hip/hip_runtime.h>
#include <math.h>

// Problem constants (reference: N=8, MA=24, DESIGN=26, RADIAL=15, SOFTENING=3, RM=5.0)
constexpr int MAC = 24;            // atoms per molecule
constexpr int DES = 26;            // sphere design points
constexpr int RAD = 15;            // radial points
constexpr int MS  = RAD * DES;     // 390 samples per atom
constexpr int MX  = MAC * MS;      // 9360 grid points per molecule
constexpr int GPB = 8;             // 32-lane groups per block (256 threads)
constexpr int PPB = 2 * GPB;       // 16 points per block (2 per group, packed)
constexpr int BPM = MX / PPB;      // 585 blocks per molecule (exact) -> n block-uniform

typedef float v2f __attribute__((ext_vector_type(2)));

__device__ __forceinline__ v2f pk_fma(v2f a, v2f b, v2f c) {
    return __builtin_elementwise_fma(a, b, c);   // -> v_pk_fma_f32
}

// xor-butterfly step within each 32-lane half (bit-mode ds_swizzle)
template <int M>
__device__ __forceinline__ float xorswz(float v) {
    return __int_as_float(__builtin_amdgcn_ds_swizzle(__float_as_int(v), (M << 10) | 0x1f));
}
// DPP cross-lane permute (VALU pipe, not DS)
template <int CTRL>
__device__ __forceinline__ float dppx(float v) {
    return __int_as_float(__builtin_amdgcn_update_dpp(
        0, __float_as_int(v), CTRL, 0xf, 0xf, true));
}

// ---------------------------------------------------------------------------
// SINGLE fused kernel — no precompute dispatch, no d_ws.
// Per block (molecule-uniform): build inv_dm table in LDS (1 barrier).
// Per 32-lane group: one packed point-pair, R10's best-known hot loop.
// Radial quadrature in fp32 closed form via half-angle:
//   th/2 = (2k+1)/120 rev;  r = 5 (s/c)^2;  w = (100*pi^2/3) s^5 / c^7
// ---------------------------------------------------------------------------
__global__ __launch_bounds__(256) void becke_fused(
    const float* __restrict__ coords,   // [nmol, 24, 3]
    const float* __restrict__ sphere,   // [26, 3]
    const float* __restrict__ sw,       // [26]
    float* __restrict__ og,             // [nmol, MX, 3]
    float* __restrict__ odv,            // [nmol, MX, 24, 3]
    float* __restrict__ ow)             // [nmol, MX]
{
    __shared__ float inv_sh[MAC][32];   // [j][i] col-padded -> conflict-free reads
    __shared__ v2f   rxp[GPB][32];      // rx pair exchange per group

    const int tid = threadIdx.x;
    const int b   = blockIdx.x;
    const int n   = b / BPM;                       // molecule (block-uniform)
    const int bm  = b - n * BPM;
    const float* cb = coords + n * MAC * 3;

    // ---- build 24x24 inverse-distance table (576 entries / 256 thr) ----
    for (int e = tid; e < MAC * MAC; e += 256) {
        int ii = e / MAC, jj = e - ii * MAC;
        float dx = cb[ii * 3 + 0] - cb[jj * 3 + 0];
        float dy = cb[ii * 3 + 1] - cb[jj * 3 + 1];
        float dz = cb[ii * 3 + 2] - cb[jj * 3 + 2];
        float dd = fmaxf(dx * dx + dy * dy + dz * dz, 1e-24f);
        // diagonal: dd=1e-24 -> inv=1e12, matches reference clip(dm,1e-12)
        inv_sh[jj][ii] = __builtin_amdgcn_rcpf(__builtin_amdgcn_sqrtf(dd));
    }
    __syncthreads();

    const int l   = tid & 31;
    const int grp = tid >> 5;
    const int s0  = bm * PPB + grp * 2;            // two points: s0, s0+1
    const bool act = (l < MAC);
    const int  i   = act ? l : (MAC - 1);

    const float cix = cb[i * 3 + 0];
    const float ciy = cb[i * 3 + 1];
    const float ciz = cb[i * 3 + 2];

    // lane's inv row: 24 conflict-free ds_read_b32 (immediate offsets)
    float inv[MAC];
    #pragma unroll
    for (int j = 0; j < MAC; ++j) inv[j] = inv_sh[j][i];

    int ap[2];
    float gx[2], gy[2], gz[2], wt[2], rx[2];
    const size_t sgb = (size_t)n * MX + s0;
    float* dvp = odv + (sgb * MAC + i) * 3;        // p-stride = 72 floats

    #pragma unroll
    for (int p = 0; p < 2; ++p) {
        int sp = s0 + p;
        ap[p] = sp / MS;                           // magic-div (const 390)
        int t  = sp - ap[p] * MS;
        int k  = t / DES;                          // radial index (const 26)
        int d  = t - k * DES;                      // design index

        // fp32 radial quadrature, half-angle closed form
        float h  = (float)(2 * k + 1) * (1.0f / 120.0f);   // theta/2 in revolutions
        float sn = __builtin_amdgcn_sinf(h);               // v_sin_f32 (rev input)
        float cn = __builtin_amdgcn_cosf(h);               // v_cos_f32
        float rc = __builtin_amdgcn_rcpf(cn);
        float t1 = sn * rc;                                // tan(theta/2)
        float u  = t1 * t1;
        float r  = 5.0f * u;                               // RM * tan^2
        float w  = 328.98681f * u * u * t1 * rc * rc;      // (100 pi^2/3) s^5/c^7
        wt[p] = sw[d] * w;

        float sx = sphere[d * 3 + 0], sy = sphere[d * 3 + 1], sz = sphere[d * 3 + 2];
        const float* cap = cb + ap[p] * 3;
        gx[p] = cap[0] + r * sx;
        gy[p] = cap[1] + r * sy;
        gz[p] = cap[2] + r * sz;

        float dx = gx[p] - cix;
        float dy = gy[p] - ciy;
        float dz = gz[p] - ciz;
        if (act) {
            dvp[p * MAC * 3 + 0] = dx;             // contiguous -> dwordx3
            dvp[p * MAC * 3 + 1] = dy;
            dvp[p * MAC * 3 + 2] = dz;
        }
        rx[p] = __builtin_amdgcn_sqrtf(dx * dx + dy * dy + dz * dz);
    }
    rxp[grp][l] = (v2f){rx[0], rx[1]};             // wave-synchronous exchange
    __builtin_amdgcn_wave_barrier();               // ordering only; DS in-order

    const v2f cm05 = {-0.5f, -0.5f}, c15 = {1.5f, 1.5f}, c05 = {0.5f, 0.5f};
    const v2f rxi = {rx[0], rx[1]};
    v2f prod = {1.0f, 1.0f};

    // Becke row product, diagonal included (s(0)=0.5 exactly, undone by *2)
    #pragma unroll
    for (int jj = 0; jj < MAC / 2; ++jj) {
        // b128 broadcast: {rx0(j0), rx1(j0), rx0(j1), rx1(j1)}
        float4 v4 = *reinterpret_cast<const float4*>(&rxp[grp][2 * jj]);
        const v2f iva = {inv[2 * jj],     inv[2 * jj]};
        const v2f ivb = {inv[2 * jj + 1], inv[2 * jj + 1]};
        v2f mu = (rxi - (v2f){v4.x, v4.y}) * iva;
        mu = mu * pk_fma(mu * mu, cm05, c15);      // soften 1
        mu = mu * pk_fma(mu * mu, cm05, c15);      // soften 2
        prod = prod * pk_fma(mu, cm05, c05);       // *= s
        v2f mv = (rxi - (v2f){v4.z, v4.w}) * ivb;
        mv = mv * pk_fma(mv * mv, cm05, c15);
        mv = mv * pk_fma(mv * mv, cm05, c15);
        prod = prod * pk_fma(mv, cm05, c05);
    }

    // mask pad lanes to 0, fold diagonal-undo factor 2
    const v2f cell = prod * (act ? (v2f){2.0f, 2.0f} : (v2f){0.0f, 0.0f});

    #pragma unroll
    for (int p = 0; p < 2; ++p) {
        float c  = (p == 0) ? cell.x : cell.y;
        float su = c;
        su += dppx<0xB1>(su);    // + lane^1 (quad_perm 1,0,3,2)
        su += dppx<0x4E>(su);    // + lane^2 (quad_perm 2,3,0,1)
        su += dppx<0x141>(su);   // + lane^4 (row_half_mirror)
        su += dppx<0x140>(su);   // + lane^8 (row_mirror)
        su += xorswz<16>(su);    // + lane^16 (single DS op)
        if (l == ap[p])          // lane a holds cell_a; rcp ok (2% slack)
            ow[sgb + p] = c * __builtin_amdgcn_rcpf(su) * wt[p];
    }

    if (l >= MAC && l < MAC + 2) {   // pad lanes 24..25 store grid points
        int p = l - MAC;
        float* gp = og + (sgb + p) * 3;
        gp[0] = gx[p]; gp[1] = gy[p]; gp[2] = gz[p];
    }
}

extern "C" void kernel_launch(void* const* d_in, const int* in_sizes, int n_in,
                              void* d_out, int out_size, void* d_ws, size_t ws_size,
                              hipStream_t stream) {
    // inputs: [0]=labels (unused), [1]=coords f32 [N,24,3],
    //         [2]=sphere f32 [26,3], [3]=sphere_weights f32 [26]
    const float* coords = (const float*)d_in[1];
    const float* sphere = (const float*)d_in[2];
    const float* sw     = (const float*)d_in[3];

    const int nmol = in_sizes[1] / (MAC * 3);   // 8

    float* o     = (float*)d_out;
    float* ogrid = o;                                        // [N, MX, 3]
    float* odv   = ogrid + (size_t)nmol * MX * 3;            // [N, MX, 24, 3]
    float* owt   = odv + (size_t)nmol * MX * MAC * 3;        // [N, MX]

    becke_fused<<<dim3(nmol * BPM), dim3(256), 0, stream>>>(
        coords, sphere, sw, ogrid, odv, owt);
}

// Round 13
// 80.450 us; speedup vs baseline: 1.0220x; 1.0130x over previous
//
#include <hip/hip_runtime.h>
#include <math.h>

// Problem constants (reference: N=8, MA=24, DESIGN=26, RADIAL=15, SOFTENING=3, RM=5.0)
constexpr int MAC = 24;            // atoms per molecule
constexpr int DES = 26;            // sphere design points
constexpr int RAD = 15;            // radial points
constexpr int MS  = RAD * DES;     // 390 samples per atom
constexpr int MX  = MAC * MS;      // 9360 grid points per molecule
constexpr int GPB = 8;             // 32-lane groups per block (256 threads)
constexpr int PPB = 2 * GPB;       // 16 points per block (2 per group, packed)
constexpr int BPM = MX / PPB;      // 585 blocks per molecule (exact) -> n block-uniform
constexpr int STR = 28;            // inv row stride (floats): 112 B, 16B-aligned,
                                   // conflict-free for b128 row reads

typedef float v2f __attribute__((ext_vector_type(2)));

__device__ __forceinline__ v2f pk_fma(v2f a, v2f b, v2f c) {
    return __builtin_elementwise_fma(a, b, c);   // -> v_pk_fma_f32
}

// xor-butterfly step within each 32-lane half (bit-mode ds_swizzle)
template <int M>
__device__ __forceinline__ float xorswz(float v) {
    return __int_as_float(__builtin_amdgcn_ds_swizzle(__float_as_int(v), (M << 10) | 0x1f));
}
// DPP cross-lane permute (VALU pipe, not DS)
template <int CTRL>
__device__ __forceinline__ float dppx(float v) {
    return __int_as_float(__builtin_amdgcn_update_dpp(
        0, __float_as_int(v), CTRL, 0xf, 0xf, true));
}

// ---------------------------------------------------------------------------
// SINGLE fused kernel — no precompute dispatch, no d_ws.
// Block builds row-major inv table [24][28] in LDS (1 barrier), lanes read
// their row with 6 conflict-free ds_read_b128. Hot loop = R10 structure:
// one packed point-pair per lane (v_pk_*), DPP + 1 ds_swizzle reduction.
// Radial quadrature fp32 closed form (validated R12):
//   th/2 = (2k+1)/120 rev;  r = 5 tan^2;  w = (100 pi^2/3) s^5/c^7
// ---------------------------------------------------------------------------
__global__ __launch_bounds__(256) void becke_fused(
    const float* __restrict__ coords,   // [nmol, 24, 3]
    const float* __restrict__ sphere,   // [26, 3]
    const float* __restrict__ sw,       // [26]
    float* __restrict__ og,             // [nmol, MX, 3]
    float* __restrict__ odv,            // [nmol, MX, 24, 3]
    float* __restrict__ ow)             // [nmol, MX]
{
    __shared__ __align__(16) float inv_sh[MAC][STR];  // 2.69 KB, row-major
    __shared__ v2f rxp[GPB][32];                      // rx pair exchange, 2 KB

    const int tid = threadIdx.x;
    const int b   = blockIdx.x;
    const int n   = b / BPM;                       // molecule (block-uniform)
    const int bm  = b - n * BPM;
    const float* cb = coords + n * MAC * 3;

    // ---- build 24x24 inverse-distance table (576 entries / 256 thr) ----
    for (int e = tid; e < MAC * MAC; e += 256) {
        int ii = e / MAC, jj = e - ii * MAC;
        float dx = cb[ii * 3 + 0] - cb[jj * 3 + 0];
        float dy = cb[ii * 3 + 1] - cb[jj * 3 + 1];
        float dz = cb[ii * 3 + 2] - cb[jj * 3 + 2];
        float dd = fmaxf(dx * dx + dy * dy + dz * dz, 1e-24f);
        // diagonal: dd=1e-24 -> inv=1e12 (matches reference clip(dm,1e-12));
        // diagonal term is never used with nonzero mu anyway (rxi-rxi=0).
        inv_sh[ii][jj] = __builtin_amdgcn_rcpf(__builtin_amdgcn_sqrtf(dd));
    }
    __syncthreads();

    const int l   = tid & 31;
    const int grp = tid >> 5;
    const int s0  = bm * PPB + grp * 2;            // two points: s0, s0+1
    const bool act = (l < MAC);
    const int  i   = act ? l : (MAC - 1);

    const float cix = cb[i * 3 + 0];
    const float ciy = cb[i * 3 + 1];
    const float ciz = cb[i * 3 + 2];

    // lane's inv row: 6 conflict-free ds_read_b128 (immediate offsets)
    float inv[MAC];
    {
        const float4* irow = reinterpret_cast<const float4*>(&inv_sh[i][0]);
        #pragma unroll
        for (int q = 0; q < MAC / 4; ++q) {
            float4 v = irow[q];
            inv[q * 4 + 0] = v.x; inv[q * 4 + 1] = v.y;
            inv[q * 4 + 2] = v.z; inv[q * 4 + 3] = v.w;
        }
    }

    int ap[2];
    float gx[2], gy[2], gz[2], wt[2], rx[2];
    const size_t sgb = (size_t)n * MX + s0;
    float* dvp = odv + (sgb * MAC + i) * 3;        // p-stride = 72 floats

    #pragma unroll
    for (int p = 0; p < 2; ++p) {
        int sp = s0 + p;
        ap[p] = sp / MS;                           // magic-div (const 390)
        int t  = sp - ap[p] * MS;
        int k  = t / DES;                          // radial index (const 26)
        int d  = t - k * DES;                      // design index

        // fp32 radial quadrature, half-angle closed form (validated R12)
        float h  = (float)(2 * k + 1) * (1.0f / 120.0f);   // theta/2, revolutions
        float sn = __builtin_amdgcn_sinf(h);               // v_sin_f32 (rev input)
        float cn = __builtin_amdgcn_cosf(h);               // v_cos_f32
        float rc = __builtin_amdgcn_rcpf(cn);
        float t1 = sn * rc;                                // tan(theta/2)
        float u  = t1 * t1;
        float r  = 5.0f * u;                               // RM * tan^2
        float w  = 328.98681f * u * u * t1 * rc * rc;      // (100 pi^2/3) s^5/c^7
        wt[p] = sw[d] * w;

        float sx = sphere[d * 3 + 0], sy = sphere[d * 3 + 1], sz = sphere[d * 3 + 2];
        const float* cap = cb + ap[p] * 3;
        gx[p] = cap[0] + r * sx;
        gy[p] = cap[1] + r * sy;
        gz[p] = cap[2] + r * sz;

        float dx = gx[p] - cix;
        float dy = gy[p] - ciy;
        float dz = gz[p] - ciz;
        if (act) {
            dvp[p * MAC * 3 + 0] = dx;             // contiguous -> dwordx3
            dvp[p * MAC * 3 + 1] = dy;
            dvp[p * MAC * 3 + 2] = dz;
        }
        rx[p] = __builtin_amdgcn_sqrtf(dx * dx + dy * dy + dz * dz);
    }
    rxp[grp][l] = (v2f){rx[0], rx[1]};             // wave-synchronous exchange
    __builtin_amdgcn_wave_barrier();               // ordering only; DS in-order

    const v2f cm05 = {-0.5f, -0.5f}, c15 = {1.5f, 1.5f}, c05 = {0.5f, 0.5f};
    const v2f rxi = {rx[0], rx[1]};
    v2f prod = {1.0f, 1.0f};

    // Becke row product, diagonal included (s(0)=0.5 exactly, undone by *2)
    #pragma unroll
    for (int jj = 0; jj < MAC / 2; ++jj) {
        // b128 broadcast: {rx0(j0), rx1(j0), rx0(j1), rx1(j1)}
        float4 v4 = *reinterpret_cast<const float4*>(&rxp[grp][2 * jj]);
        const v2f iva = {inv[2 * jj],     inv[2 * jj]};
        const v2f ivb = {inv[2 * jj + 1], inv[2 * jj + 1]};
        v2f mu = (rxi - (v2f){v4.x, v4.y}) * iva;
        mu = mu * pk_fma(mu * mu, cm05, c15);      // soften 1
        mu = mu * pk_fma(mu * mu, cm05, c15);      // soften 2
        prod = prod * pk_fma(mu, cm05, c05);       // *= s
        v2f mv = (rxi - (v2f){v4.z, v4.w}) * ivb;
        mv = mv * pk_fma(mv * mv, cm05, c15);
        mv = mv * pk_fma(mv * mv, cm05, c15);
        prod = prod * pk_fma(mv, cm05, c05);
    }

    // mask pad lanes to 0, fold diagonal-undo factor 2
    const v2f cell = prod * (act ? (v2f){2.0f, 2.0f} : (v2f){0.0f, 0.0f});

    #pragma unroll
    for (int p = 0; p < 2; ++p) {
        float c  = (p == 0) ? cell.x : cell.y;
        float su = c;
        su += dppx<0xB1>(su);    // + lane^1 (quad_perm 1,0,3,2)
        su += dppx<0x4E>(su);    // + lane^2 (quad_perm 2,3,0,1)
        su += dppx<0x141>(su);   // + lane^4 (row_half_mirror)
        su += dppx<0x140>(su);   // + lane^8 (row_mirror)
        su += xorswz<16>(su);    // + lane^16 (single DS op)
        if (l == ap[p])          // lane a holds cell_a; rcp ok (2% slack)
            ow[sgb + p] = c * __builtin_amdgcn_rcpf(su) * wt[p];
    }

    if (l >= MAC && l < MAC + 2) {   // pad lanes 24..25 store grid points
        int p = l - MAC;
        float* gp = og + (sgb + p) * 3;
        gp[0] = gx[p]; gp[1] = gy[p]; gp[2] = gz[p];
    }
}

extern "C" void kernel_launch(void* const* d_in, const int* in_sizes, int n_in,
                              void* d_out, int out_size, void* d_ws, size_t ws_size,
                              hipStream_t stream) {
    // inputs: [0]=labels (unused), [1]=coords f32 [N,24,3],
    //         [2]=sphere f32 [26,3], [3]=sphere_weights f32 [26]
    const float* coords = (const float*)d_in[1];
    const float* sphere = (const float*)d_in[2];
    const float* sw     = (const float*)d_in[3];

    const int nmol = in_sizes[1] / (MAC * 3);   // 8

    float* o     = (float*)d_out;
    float* ogrid = o;                                        // [N, MX, 3]
    float* odv   = ogrid + (size_t)nmol * MX * 3;            // [N, MX, 24, 3]
    float* owt   = odv + (size_t)nmol * MX * MAC * 3;        // [N, MX]

    becke_fused<<<dim3(nmol * BPM), dim3(256), 0, stream>>>(
        coords, sphere, sw, ogrid, odv, owt);
}